// Round 8
// baseline (393.066 us; speedup 1.0000x reference)
//
#include <hip/hip_runtime.h>
#include <hip/hip_bf16.h>

#define NN 8192
#define DD 128

typedef short short8 __attribute__((ext_vector_type(8)));
typedef __bf16 bf16x8 __attribute__((ext_vector_type(8)));
typedef float f32x4 __attribute__((ext_vector_type(4)));

// unit-norm simplification (x2=y2=1):
//   d = 1 + c^2 - 2cs ;  q = nd^2 = 2c(1-s)/d ;  1-q = (1-c)^2/d exactly
//   rr = (1+nd)/(1-nd) = (1+nd)^2 * d/(1-c)^2
//   adc = -dist/T = KL*log2(rr) ; e = exp(adc) = exp2(KE*log2(rr))
#define MKc (-0.110803324099723f)   // -2c/(1-c)^2
#define PKc (0.110803324099723f)    // +2c/(1-c)^2
#define C1Kc (1.110803324099723f)   // (1+c^2)/(1-c)^2
#define KEc (-8.944271909999159f)   // -1/(sqrt_c*T)
#define KLc (-6.199696797323639f)   // KE*ln2

// ---------------- prep: normalize 16 rows/block -> bf16; zero accumulators ----------------
__global__ __launch_bounds__(256) void prep_kernel(const float* __restrict__ x,
                                                   __hip_bfloat16* __restrict__ fb,
                                                   float* __restrict__ totg,
                                                   float* __restrict__ tposg,
                                                   int* __restrict__ counter) {
  int r = threadIdx.x >> 4, sub = threadIdx.x & 15;
  int row = blockIdx.x * 16 + r;
  const float4 a = *(const float4*)(x + (size_t)row * DD + sub * 8);
  const float4 b = *(const float4*)(x + (size_t)row * DD + sub * 8 + 4);
  float ss = a.x * a.x + a.y * a.y + a.z * a.z + a.w * a.w +
             b.x * b.x + b.y * b.y + b.z * b.z + b.w * b.w;
  for (int off = 1; off < 16; off <<= 1) ss += __shfl_xor(ss, off, 16);
  float inv = 1.0f / fmaxf(sqrtf(ss), 1e-12f);
  float va[8] = {a.x, a.y, a.z, a.w, b.x, b.y, b.z, b.w};
  short8 h;
  for (int j = 0; j < 8; j++) {
    __hip_bfloat16 t = __float2bfloat16(va[j] * inv);
    h[j] = __builtin_bit_cast(short, t);
  }
  *(short8*)((short*)fb + (size_t)row * DD + sub * 8) = h;
  // zero the per-row accumulators + done-counter (replaces a memset node)
  if (threadIdx.x < 16) {
    totg[blockIdx.x * 16 + threadIdx.x] = 0.f;
    tposg[blockIdx.x * 16 + threadIdx.x] = 0.f;
  }
  if (blockIdx.x == 0 && threadIdx.x == 0) *counter = 0;
}

// ---------------- fused: 256 rows x 256 cols per block, 4 blocks/CU; last block finalizes ----------------
__global__ __launch_bounds__(256, 4) void fused_kernel(
    const __hip_bfloat16* __restrict__ fbg,
    const int* __restrict__ plab, const int* __restrict__ slab,
    float* __restrict__ totg, float* __restrict__ tposg,
    int* __restrict__ counter, float* __restrict__ out) {
  __shared__ short Bbuf[64 * 128];    // 16 KB, XOR-swizzled B tile
  __shared__ int plc[256], slc[256];  // 2 KB

  const int tid = threadIdx.x;
  const int w = tid >> 6;
  const int lane = tid & 63;
  const int lrow = lane & 15;
  const int quad = lane >> 4;
  const int R0 = blockIdx.y * 256;
  const int C0 = blockIdx.x * 256;

  plc[tid] = plab[C0 + tid];
  slc[tid] = slab[C0 + tid];

  // A fragments + row labels (wave w owns rows R0 + w*64 .. +63, 4 strips of 16)
  bf16x8 af[4][4];
  int plr[4][4], slr[4][4];
  for (int strip = 0; strip < 4; strip++) {
    const short* fa = (const short*)fbg + (size_t)(R0 + w * 64 + strip * 16 + lrow) * DD;
    for (int kk = 0; kk < 4; kk++)
      af[strip][kk] = __builtin_bit_cast(bf16x8, *(const short8*)(fa + kk * 32 + quad * 8));
    for (int r = 0; r < 4; r++) {
      int rowg = R0 + w * 64 + strip * 16 + quad * 4 + r;
      plr[strip][r] = plab[rowg];
      slr[strip][r] = slab[rowg];
    }
  }

  float tot[4][4], lgs[4][4];
  for (int s_ = 0; s_ < 4; s_++)
    for (int r = 0; r < 4; r++) { tot[s_][r] = 0.f; lgs[s_][r] = 0.f; }

  for (int tile = 0; tile < 4; tile++) {
    const int CT = C0 + tile * 64;
    __syncthreads();  // previous tile's readers done before overwriting Bbuf
    {
      const short* gb = (const short*)fbg + (size_t)CT * DD;
      for (int i = 0; i < 4; i++) {
        int o = tid + i * 256;  // row-major 16B-unit index
        int row = o >> 4, uu = o & 15;
        int u = (row << 4) + (uu ^ (row & 15));
        *(short8*)(Bbuf + u * 8) = *(const short8*)(gb + o * 8);
      }
    }
    __syncthreads();

    const int lb = tile * 64;
    for (int ct = 0; ct < 4; ct++) {
      const int rt = ct * 16 + lrow;
      bf16x8 bf[4];
      for (int kk = 0; kk < 4; kk++) {
        int u = (rt << 4) + ((kk * 4 + quad) ^ lrow);
        bf[kk] = __builtin_bit_cast(bf16x8, *(const short8*)(Bbuf + u * 8));
      }
      f32x4 acc[4];
      for (int strip = 0; strip < 4; strip++) {
        f32x4 a0 = {0.f, 0.f, 0.f, 0.f};
        for (int kk = 0; kk < 4; kk++)
          a0 = __builtin_amdgcn_mfma_f32_16x16x32_bf16(af[strip][kk], bf[kk], a0, 0, 0, 0);
        acc[strip] = a0;
      }
      const int colg = CT + rt;
      const int pc = plc[lb + rt];
      const int sc = slc[lb + rt];
      for (int strip = 0; strip < 4; strip++) {
        for (int r = 0; r < 4; r++) {
          float s = acc[strip][r];
          float tK = fmaxf(fmaf(s, MKc, PKc), 0.0f);  // 2cK*(1-s), clamped (diag noise)
          float dk = fmaf(s, MKc, C1Kc);              // d*K
          float m = fmaxf(tK * dk, 1e-30f);
          float nd = tK * __builtin_amdgcn_rsqf(m);   // sqrt(tK/dk), 0-safe
          float p1 = 1.0f + nd;
          float rr = p1 * p1 * dk;
          float lg = __log2f(rr);
          float e = exp2f(KEc * lg);
          int rowg = R0 + w * 64 + strip * 16 + quad * 4 + r;
          bool offd = (colg != rowg);
          bool same = (pc == plr[strip][r]) || (sc == slr[strip][r]);
          tot[strip][r] += offd ? e : 0.0f;
          lgs[strip][r] += (same && offd) ? lg : 0.0f;
        }
      }
    }
  }

  // 16-lane (column) reduce, per-row atomic partials
  for (int strip = 0; strip < 4; strip++) {
    for (int r = 0; r < 4; r++) {
      float t = tot[strip][r], g = lgs[strip][r];
      for (int off = 1; off < 16; off <<= 1) {
        t += __shfl_xor(t, off, 16);
        g += __shfl_xor(g, off, 16);
      }
      if (lrow == 0) {
        int rowg = R0 + w * 64 + strip * 16 + quad * 4 + r;
        atomicAdd(&totg[rowg], t);
        atomicAdd(&tposg[rowg], g);
      }
    }
  }

  // ---------------- last block finalizes (device-scope handshake) ----------------
  __shared__ int isLast;
  __threadfence();
  if (tid == 0) isLast = (atomicAdd(counter, 1) == 32 * 32 - 1) ? 1 : 0;
  __syncthreads();
  if (isLast) {
    __threadfence();
    __shared__ int hist[512];
    __shared__ int cntP[32], cntS[16];
    __shared__ float redP[4], redV[4];
    for (int i = tid; i < 512; i += 256) hist[i] = 0;
    __syncthreads();
    for (int i = tid; i < NN; i += 256)
      atomicAdd(&hist[plab[i] * 16 + slab[i]], 1);
    __syncthreads();
    if (tid < 32) {
      int s = 0;
      for (int j = 0; j < 16; j++) s += hist[tid * 16 + j];
      cntP[tid] = s;
    } else if (tid >= 64 && tid < 80) {
      int s = 0;
      for (int j = 0; j < 32; j++) s += hist[j * 16 + (tid - 64)];
      cntS[tid - 64] = s;
    }
    __syncthreads();
    float accP = 0.f, accV = 0.f;
    for (int i = tid; i < NN; i += 256) {
      int pl = plab[i], sl = slab[i];
      int np = cntP[pl] + cntS[sl] - hist[pl * 16 + sl] - 1;
      if (np > 0) {
        accP += (KLc * tposg[i]) / (float)np - __logf(totg[i] + 1e-8f);
        accV += 1.f;
      }
    }
    for (int off = 32; off; off >>= 1) {
      accP += __shfl_xor(accP, off, 64);
      accV += __shfl_xor(accV, off, 64);
    }
    int wv = tid >> 6;
    if ((tid & 63) == 0) { redP[wv] = accP; redV[wv] = accV; }
    __syncthreads();
    if (tid == 0) {
      float sp = redP[0] + redP[1] + redP[2] + redP[3];
      float sv = redV[0] + redV[1] + redV[2] + redV[3];
      float loss = -(sp / fmaxf(sv, 1.0f)) * 0.5f;  // * TEMPERATURE
      if (sv <= 0.0f || !__builtin_isfinite(loss)) loss = 0.0f;
      out[0] = loss;
    }
  }
}

extern "C" void kernel_launch(void* const* d_in, const int* in_sizes, int n_in,
                              void* d_out, int out_size, void* d_ws, size_t ws_size,
                              hipStream_t stream) {
  const float* x = (const float*)d_in[0];
  const int* pl = (const int*)d_in[1];
  const int* sl = (const int*)d_in[2];
  char* ws = (char*)d_ws;
  __hip_bfloat16* fb = (__hip_bfloat16*)ws;    // 2,097,152 B
  float* totg = (float*)(ws + 2097152);        // 32 KB
  float* tposg = (float*)(ws + 2129920);       // 32 KB
  int* counter = (int*)(ws + 2162688);         // 4 B

  prep_kernel<<<NN / 16, 256, 0, stream>>>(x, fb, totg, tposg, counter);
  fused_kernel<<<dim3(32, 32), 256, 0, stream>>>(fb, pl, sl, totg, tposg, counter,
                                                 (float*)d_out);
}

// Round 9
// 304.876 us; speedup vs baseline: 1.2893x; 1.2893x over previous
//
#include <hip/hip_runtime.h>
#include <hip/hip_bf16.h>

#define NN 8192
#define DD 128

typedef short short8 __attribute__((ext_vector_type(8)));
typedef __bf16 bf16x8 __attribute__((ext_vector_type(8)));
typedef float f32x4 __attribute__((ext_vector_type(4)));

// unit-norm simplification (x2=y2=1):
//   d = 1 + c^2 - 2cs ;  q = nd^2 = 2c(1-s)/d ;  1-q = (1-c)^2/d exactly
//   rr = (1+nd)/(1-nd) = (1+nd)^2 * d/(1-c)^2
//   adc = -dist/T = KL*log2(rr) ; e = exp(adc) = exp2(KE*log2(rr))
#define MKc (-0.110803324099723f)   // -2c/(1-c)^2
#define PKc (0.110803324099723f)    // +2c/(1-c)^2
#define C1Kc (1.110803324099723f)   // (1+c^2)/(1-c)^2
#define KEc (-8.944271909999159f)   // -1/(sqrt_c*T)
#define KLc (-6.199696797323639f)   // KE*ln2

// ---------------- prep: normalize 16 rows/block -> bf16; zero accumulators ----------------
__global__ __launch_bounds__(256) void prep_kernel(const float* __restrict__ x,
                                                   __hip_bfloat16* __restrict__ fb,
                                                   float* __restrict__ totg,
                                                   float* __restrict__ tposg) {
  int r = threadIdx.x >> 4, sub = threadIdx.x & 15;
  int row = blockIdx.x * 16 + r;
  const float4 a = *(const float4*)(x + (size_t)row * DD + sub * 8);
  const float4 b = *(const float4*)(x + (size_t)row * DD + sub * 8 + 4);
  float ss = a.x * a.x + a.y * a.y + a.z * a.z + a.w * a.w +
             b.x * b.x + b.y * b.y + b.z * b.z + b.w * b.w;
  for (int off = 1; off < 16; off <<= 1) ss += __shfl_xor(ss, off, 16);
  float inv = 1.0f / fmaxf(sqrtf(ss), 1e-12f);
  float va[8] = {a.x, a.y, a.z, a.w, b.x, b.y, b.z, b.w};
  short8 h;
  for (int j = 0; j < 8; j++) {
    __hip_bfloat16 t = __float2bfloat16(va[j] * inv);
    h[j] = __builtin_bit_cast(short, t);
  }
  *(short8*)((short*)fb + (size_t)row * DD + sub * 8) = h;
  // zero the per-row accumulators (replaces a memset node)
  if (threadIdx.x < 16) {
    totg[blockIdx.x * 16 + threadIdx.x] = 0.f;
    tposg[blockIdx.x * 16 + threadIdx.x] = 0.f;
  }
}

// ---------------- fused: 256 rows x 256 cols per block, 4 blocks/CU ----------------
__global__ __launch_bounds__(256, 4) void fused_kernel(
    const __hip_bfloat16* __restrict__ fbg,
    const int* __restrict__ plab, const int* __restrict__ slab,
    float* __restrict__ totg, float* __restrict__ tposg) {
  __shared__ short Bbuf[64 * 128];    // 16 KB, XOR-swizzled B tile
  __shared__ int plc[256], slc[256];  // 2 KB

  const int tid = threadIdx.x;
  const int w = tid >> 6;
  const int lane = tid & 63;
  const int lrow = lane & 15;
  const int quad = lane >> 4;
  const int R0 = blockIdx.y * 256;
  const int C0 = blockIdx.x * 256;

  plc[tid] = plab[C0 + tid];
  slc[tid] = slab[C0 + tid];

  // A fragments + row labels (wave w owns rows R0 + w*64 .. +63, 4 strips of 16)
  bf16x8 af[4][4];
  int plr[4][4], slr[4][4];
  for (int strip = 0; strip < 4; strip++) {
    const short* fa = (const short*)fbg + (size_t)(R0 + w * 64 + strip * 16 + lrow) * DD;
    for (int kk = 0; kk < 4; kk++)
      af[strip][kk] = __builtin_bit_cast(bf16x8, *(const short8*)(fa + kk * 32 + quad * 8));
    for (int r = 0; r < 4; r++) {
      int rowg = R0 + w * 64 + strip * 16 + quad * 4 + r;
      plr[strip][r] = plab[rowg];
      slr[strip][r] = slab[rowg];
    }
  }

  float tot[4][4], lgs[4][4];
  for (int s_ = 0; s_ < 4; s_++)
    for (int r = 0; r < 4; r++) { tot[s_][r] = 0.f; lgs[s_][r] = 0.f; }

  for (int tile = 0; tile < 4; tile++) {
    const int CT = C0 + tile * 64;
    __syncthreads();  // previous tile's readers done before overwriting Bbuf
    {
      const short* gb = (const short*)fbg + (size_t)CT * DD;
      for (int i = 0; i < 4; i++) {
        int o = tid + i * 256;  // row-major 16B-unit index
        int row = o >> 4, uu = o & 15;
        int u = (row << 4) + (uu ^ (row & 15));
        *(short8*)(Bbuf + u * 8) = *(const short8*)(gb + o * 8);
      }
    }
    __syncthreads();

    const int lb = tile * 64;
    for (int ct = 0; ct < 4; ct++) {
      const int rt = ct * 16 + lrow;
      bf16x8 bf[4];
      for (int kk = 0; kk < 4; kk++) {
        int u = (rt << 4) + ((kk * 4 + quad) ^ lrow);
        bf[kk] = __builtin_bit_cast(bf16x8, *(const short8*)(Bbuf + u * 8));
      }
      f32x4 acc[4];
      for (int strip = 0; strip < 4; strip++) {
        f32x4 a0 = {0.f, 0.f, 0.f, 0.f};
        for (int kk = 0; kk < 4; kk++)
          a0 = __builtin_amdgcn_mfma_f32_16x16x32_bf16(af[strip][kk], bf[kk], a0, 0, 0, 0);
        acc[strip] = a0;
      }
      const int colg = CT + rt;
      const int pc = plc[lb + rt];
      const int sc = slc[lb + rt];
      for (int strip = 0; strip < 4; strip++) {
        for (int r = 0; r < 4; r++) {
          float s = acc[strip][r];
          float tK = fmaxf(fmaf(s, MKc, PKc), 0.0f);  // 2cK*(1-s), clamped (diag noise)
          float dk = fmaf(s, MKc, C1Kc);              // d*K
          float m = fmaxf(tK * dk, 1e-30f);
          float nd = tK * __builtin_amdgcn_rsqf(m);   // sqrt(tK/dk), 0-safe
          float p1 = 1.0f + nd;
          float rr = p1 * p1 * dk;
          float lg = __log2f(rr);
          float e = exp2f(KEc * lg);
          int rowg = R0 + w * 64 + strip * 16 + quad * 4 + r;
          bool offd = (colg != rowg);
          bool same = (pc == plr[strip][r]) || (sc == slr[strip][r]);
          tot[strip][r] += offd ? e : 0.0f;
          lgs[strip][r] += (same && offd) ? lg : 0.0f;
        }
      }
    }
  }

  // 16-lane (column) reduce, per-row atomic partials
  for (int strip = 0; strip < 4; strip++) {
    for (int r = 0; r < 4; r++) {
      float t = tot[strip][r], g = lgs[strip][r];
      for (int off = 1; off < 16; off <<= 1) {
        t += __shfl_xor(t, off, 16);
        g += __shfl_xor(g, off, 16);
      }
      if (lrow == 0) {
        int rowg = R0 + w * 64 + strip * 16 + quad * 4 + r;
        atomicAdd(&totg[rowg], t);
        atomicAdd(&tposg[rowg], g);
      }
    }
  }
}

// ---------------- finalize stage 1: 32 blocks, 1 row/thread ----------------
__global__ __launch_bounds__(256) void final1_k(const float* __restrict__ totg,
                                                const float* __restrict__ tposg,
                                                const int* __restrict__ plab,
                                                const int* __restrict__ slab,
                                                float* __restrict__ scal) {
  __shared__ int hist[512];
  __shared__ int cntP[32], cntS[16];
  __shared__ float redP[4], redV[4];
  const int tid = threadIdx.x;
  for (int i = tid; i < 512; i += 256) hist[i] = 0;
  __syncthreads();
  for (int i = tid; i < NN; i += 256)
    atomicAdd(&hist[plab[i] * 16 + slab[i]], 1);
  __syncthreads();
  if (tid < 32) {
    int s = 0;
    for (int j = 0; j < 16; j++) s += hist[tid * 16 + j];
    cntP[tid] = s;
  } else if (tid >= 64 && tid < 80) {
    int s = 0;
    for (int j = 0; j < 32; j++) s += hist[j * 16 + (tid - 64)];
    cntS[tid - 64] = s;
  }
  __syncthreads();
  const int i = blockIdx.x * 256 + tid;
  const int pl = plab[i], sl = slab[i];
  const int np = cntP[pl] + cntS[sl] - hist[pl * 16 + sl] - 1;
  float accP = 0.f, accV = 0.f;
  if (np > 0) {
    accP = (KLc * tposg[i]) / (float)np - __logf(totg[i] + 1e-8f);
    accV = 1.f;
  }
  for (int off = 32; off; off >>= 1) {
    accP += __shfl_xor(accP, off, 64);
    accV += __shfl_xor(accV, off, 64);
  }
  int wv = tid >> 6;
  if ((tid & 63) == 0) { redP[wv] = accP; redV[wv] = accV; }
  __syncthreads();
  if (tid == 0) {
    atomicAdd(&scal[0], redP[0] + redP[1] + redP[2] + redP[3]);
    atomicAdd(&scal[1], redV[0] + redV[1] + redV[2] + redV[3]);
  }
}

// ---------------- finalize stage 2 ----------------
__global__ void final2_k(const float* __restrict__ scal, float* __restrict__ out) {
  float sp = scal[0], sv = scal[1];
  float loss = -(sp / fmaxf(sv, 1.0f)) * 0.5f;  // * TEMPERATURE
  if (sv <= 0.0f || !__builtin_isfinite(loss)) loss = 0.0f;
  out[0] = loss;
}

extern "C" void kernel_launch(void* const* d_in, const int* in_sizes, int n_in,
                              void* d_out, int out_size, void* d_ws, size_t ws_size,
                              hipStream_t stream) {
  const float* x = (const float*)d_in[0];
  const int* pl = (const int*)d_in[1];
  const int* sl = (const int*)d_in[2];
  char* ws = (char*)d_ws;
  __hip_bfloat16* fb = (__hip_bfloat16*)ws;    // 2,097,152 B
  float* totg = (float*)(ws + 2097152);        // 32 KB
  float* tposg = (float*)(ws + 2129920);       // 32 KB
  float* scal = (float*)(ws + 2162688);        // 8 B

  (void)hipMemsetAsync(scal, 0, 8, stream);

  prep_kernel<<<NN / 16, 256, 0, stream>>>(x, fb, totg, tposg);
  fused_kernel<<<dim3(32, 32), 256, 0, stream>>>(fb, pl, sl, totg, tposg);
  final1_k<<<NN / 256, 256, 0, stream>>>(totg, tposg, pl, sl, scal);
  final2_k<<<1, 1, 0, stream>>>(scal, (float*)d_out);
}

// Round 10
// 139.981 us; speedup vs baseline: 2.8080x; 2.1780x over previous
//
#include <hip/hip_runtime.h>
#include <hip/hip_bf16.h>

#define NN 8192
#define DD 128

typedef short short8 __attribute__((ext_vector_type(8)));
typedef __bf16 bf16x8 __attribute__((ext_vector_type(8)));
typedef float f32x4 __attribute__((ext_vector_type(4)));

// unit-norm simplification (x2=y2=1):
//   d = 1 + c^2 - 2cs ;  q = nd^2 = 2c(1-s)/d ;  1-q = (1-c)^2/d exactly
//   rr = (1+nd)/(1-nd) = (1+nd)^2 * d/(1-c)^2
//   adc = -dist/T = KL*log2(rr) ; e = exp(adc) = exp2(KE*log2(rr))
#define MKc (-0.110803324099723f)   // -2c/(1-c)^2
#define PKc (0.110803324099723f)    // +2c/(1-c)^2
#define C1Kc (1.110803324099723f)   // (1+c^2)/(1-c)^2
#define KEc (-8.944271909999159f)   // -1/(sqrt_c*T)
#define KLc (-6.199696797323639f)   // KE*ln2

// ---------------- prep: normalize 16 rows/block -> bf16; zero accumulators ----------------
__global__ __launch_bounds__(256) void prep_kernel(const float* __restrict__ x,
                                                   __hip_bfloat16* __restrict__ fb,
                                                   float* __restrict__ totg,
                                                   float* __restrict__ tposg,
                                                   float* __restrict__ scal) {
  int r = threadIdx.x >> 4, sub = threadIdx.x & 15;
  int row = blockIdx.x * 16 + r;
  const float4 a = *(const float4*)(x + (size_t)row * DD + sub * 8);
  const float4 b = *(const float4*)(x + (size_t)row * DD + sub * 8 + 4);
  float ss = a.x * a.x + a.y * a.y + a.z * a.z + a.w * a.w +
             b.x * b.x + b.y * b.y + b.z * b.z + b.w * b.w;
  for (int off = 1; off < 16; off <<= 1) ss += __shfl_xor(ss, off, 16);
  float inv = 1.0f / fmaxf(sqrtf(ss), 1e-12f);
  float va[8] = {a.x, a.y, a.z, a.w, b.x, b.y, b.z, b.w};
  short8 h;
  for (int j = 0; j < 8; j++) {
    __hip_bfloat16 t = __float2bfloat16(va[j] * inv);
    h[j] = __builtin_bit_cast(short, t);
  }
  *(short8*)((short*)fb + (size_t)row * DD + sub * 8) = h;
  // zero the per-row accumulators + scalar slots (replaces memset nodes)
  if (threadIdx.x < 16) {
    totg[blockIdx.x * 16 + threadIdx.x] = 0.f;
    tposg[blockIdx.x * 16 + threadIdx.x] = 0.f;
  }
  if (blockIdx.x == 0 && threadIdx.x < 2) scal[threadIdx.x] = 0.f;
}

// ---------------- fused: 128 rows x 512 cols per block, NO LDS staging, no main-loop barriers ----------------
// B fragments are loaded directly from global (fbg is 2 MB, L2-resident; 16-col
// working set = 4 KB, L1 absorbs the 4-wave redundancy). VGPR-safe config:
// launch_bounds(256,2) -> cap 256 (the (256,4) variants made the allocator pick
// 64 VGPRs and spill ~1 GB of scratch traffic -- R8/R9 post-mortem).
__global__ __launch_bounds__(256, 2) void fused_kernel(
    const __hip_bfloat16* __restrict__ fbg,
    const int* __restrict__ plab, const int* __restrict__ slab,
    float* __restrict__ totg, float* __restrict__ tposg) {
  __shared__ int plc[512], slc[512];  // 4 KB: column labels

  const int tid = threadIdx.x;
  const int w = tid >> 6;
  const int lane = tid & 63;
  const int lrow = lane & 15;
  const int quad = lane >> 4;
  const int R0 = blockIdx.y * 128;
  const int C0 = blockIdx.x * 512;

  for (int i = tid; i < 512; i += 256) {
    plc[i] = plab[C0 + i];
    slc[i] = slab[C0 + i];
  }

  // A fragments + row labels (wave w owns rows R0 + w*32 .. +31, 2 strips of 16)
  bf16x8 af[2][4];
  int plr[2][4], slr[2][4];
  for (int strip = 0; strip < 2; strip++) {
    const short* fa = (const short*)fbg + (size_t)(R0 + w * 32 + strip * 16 + lrow) * DD;
    for (int kk = 0; kk < 4; kk++)
      af[strip][kk] = __builtin_bit_cast(bf16x8, *(const short8*)(fa + kk * 32 + quad * 8));
    for (int r = 0; r < 4; r++) {
      int rowg = R0 + w * 32 + strip * 16 + quad * 4 + r;
      plr[strip][r] = plab[rowg];
      slr[strip][r] = slab[rowg];
    }
  }
  __syncthreads();  // labels staged (the only barrier in this kernel)

  float tot[2][4], lgs[2][4];
  for (int s_ = 0; s_ < 2; s_++)
    for (int r = 0; r < 4; r++) { tot[s_][r] = 0.f; lgs[s_][r] = 0.f; }

  for (int ct = 0; ct < 32; ct++) {
    const int lc = ct * 16 + lrow;
    const int colg = C0 + lc;
    // B fragment straight from global: bf[kk][j] = f[colg][kk*32 + quad*8 + j]
    const short* bp = (const short*)fbg + (size_t)colg * DD + quad * 8;
    bf16x8 bf[4];
    for (int kk = 0; kk < 4; kk++)
      bf[kk] = __builtin_bit_cast(bf16x8, *(const short8*)(bp + kk * 32));

    f32x4 acc[2];
    for (int strip = 0; strip < 2; strip++) {
      f32x4 a0 = {0.f, 0.f, 0.f, 0.f};
      for (int kk = 0; kk < 4; kk++)
        a0 = __builtin_amdgcn_mfma_f32_16x16x32_bf16(af[strip][kk], bf[kk], a0, 0, 0, 0);
      acc[strip] = a0;
    }
    const int pc = plc[lc];
    const int sc = slc[lc];
    for (int strip = 0; strip < 2; strip++) {
      for (int r = 0; r < 4; r++) {
        float s = acc[strip][r];
        float tK = fmaxf(fmaf(s, MKc, PKc), 0.0f);  // 2cK*(1-s), clamped (diag noise)
        float dk = fmaf(s, MKc, C1Kc);              // d*K
        float m = fmaxf(tK * dk, 1e-30f);
        float nd = tK * __builtin_amdgcn_rsqf(m);   // sqrt(tK/dk), 0-safe
        float p1 = 1.0f + nd;
        float rr = p1 * p1 * dk;
        float lg = __log2f(rr);
        float e = exp2f(KEc * lg);
        int rowg = R0 + w * 32 + strip * 16 + quad * 4 + r;
        bool offd = (colg != rowg);
        bool same = (pc == plr[strip][r]) || (sc == slr[strip][r]);
        tot[strip][r] += offd ? e : 0.0f;
        lgs[strip][r] += (same && offd) ? lg : 0.0f;
      }
    }
  }

  // 16-lane (column) reduce, per-row atomic partials
  for (int strip = 0; strip < 2; strip++) {
    for (int r = 0; r < 4; r++) {
      float t = tot[strip][r], g = lgs[strip][r];
      for (int off = 1; off < 16; off <<= 1) {
        t += __shfl_xor(t, off, 16);
        g += __shfl_xor(g, off, 16);
      }
      if (lrow == 0) {
        int rowg = R0 + w * 32 + strip * 16 + quad * 4 + r;
        atomicAdd(&totg[rowg], t);
        atomicAdd(&tposg[rowg], g);
      }
    }
  }
}

// ---------------- finalize stage 1: 32 blocks, 1 row/thread ----------------
__global__ __launch_bounds__(256) void final1_k(const float* __restrict__ totg,
                                                const float* __restrict__ tposg,
                                                const int* __restrict__ plab,
                                                const int* __restrict__ slab,
                                                float* __restrict__ scal) {
  __shared__ int hist[512];
  __shared__ int cntP[32], cntS[16];
  __shared__ float redP[4], redV[4];
  const int tid = threadIdx.x;
  for (int i = tid; i < 512; i += 256) hist[i] = 0;
  __syncthreads();
  for (int i = tid; i < NN; i += 256)
    atomicAdd(&hist[plab[i] * 16 + slab[i]], 1);
  __syncthreads();
  if (tid < 32) {
    int s = 0;
    for (int j = 0; j < 16; j++) s += hist[tid * 16 + j];
    cntP[tid] = s;
  } else if (tid >= 64 && tid < 80) {
    int s = 0;
    for (int j = 0; j < 32; j++) s += hist[j * 16 + (tid - 64)];
    cntS[tid - 64] = s;
  }
  __syncthreads();
  const int i = blockIdx.x * 256 + tid;
  const int pl = plab[i], sl = slab[i];
  const int np = cntP[pl] + cntS[sl] - hist[pl * 16 + sl] - 1;
  float accP = 0.f, accV = 0.f;
  if (np > 0) {
    accP = (KLc * tposg[i]) / (float)np - __logf(totg[i] + 1e-8f);
    accV = 1.f;
  }
  for (int off = 32; off; off >>= 1) {
    accP += __shfl_xor(accP, off, 64);
    accV += __shfl_xor(accV, off, 64);
  }
  int wv = tid >> 6;
  if ((tid & 63) == 0) { redP[wv] = accP; redV[wv] = accV; }
  __syncthreads();
  if (tid == 0) {
    atomicAdd(&scal[0], redP[0] + redP[1] + redP[2] + redP[3]);
    atomicAdd(&scal[1], redV[0] + redV[1] + redV[2] + redV[3]);
  }
}

// ---------------- finalize stage 2 ----------------
__global__ void final2_k(const float* __restrict__ scal, float* __restrict__ out) {
  float sp = scal[0], sv = scal[1];
  float loss = -(sp / fmaxf(sv, 1.0f)) * 0.5f;  // * TEMPERATURE
  if (sv <= 0.0f || !__builtin_isfinite(loss)) loss = 0.0f;
  out[0] = loss;
}

extern "C" void kernel_launch(void* const* d_in, const int* in_sizes, int n_in,
                              void* d_out, int out_size, void* d_ws, size_t ws_size,
                              hipStream_t stream) {
  const float* x = (const float*)d_in[0];
  const int* pl = (const int*)d_in[1];
  const int* sl = (const int*)d_in[2];
  char* ws = (char*)d_ws;
  __hip_bfloat16* fb = (__hip_bfloat16*)ws;    // 2,097,152 B
  float* totg = (float*)(ws + 2097152);        // 32 KB
  float* tposg = (float*)(ws + 2129920);       // 32 KB
  float* scal = (float*)(ws + 2162688);        // 8 B

  prep_kernel<<<NN / 16, 256, 0, stream>>>(x, fb, totg, tposg, scal);
  fused_kernel<<<dim3(16, 64), 256, 0, stream>>>(fb, pl, sl, totg, tposg);
  final1_k<<<NN / 256, 256, 0, stream>>>(totg, tposg, pl, sl, scal);
  final2_k<<<1, 1, 0, stream>>>(scal, (float*)d_out);
}